// Round 12
// baseline (583.169 us; speedup 1.0000x reference)
//
#include <hip/hip_runtime.h>

typedef unsigned short u16;
typedef unsigned int u32;
typedef __attribute__((ext_vector_type(8))) short short8;
typedef __attribute__((ext_vector_type(4))) float f32x4;
typedef __attribute__((ext_vector_type(2))) float f32x2;

#define BB 512
#define TT 128
#define DD 128
#define HH 4
#define NBB 2
#define BT (BB*TT)
#define EPSF 1e-5f
#define LOG2E 1.4426950408889634f

__device__ __forceinline__ float bf2f(u16 u){ return __uint_as_float(((u32)u) << 16); }
__device__ __forceinline__ u16 f2bf(float f){
  u32 x = __float_as_uint(f);
  u32 r = x + 0x7fffu + ((x >> 16) & 1u);
  return (u16)(r >> 16);
}
__device__ __forceinline__ float bcastf(float v, int lane){
  return __uint_as_float(__builtin_amdgcn_readlane(__float_as_uint(v), lane));
}
// gelu (tanh approx) with rcp/exp2 only
__device__ __forceinline__ float gelu_fast(float x){
  float u = 0.7978845608028654f * (x + 0.044715f * x * x * x);
  float e2 = __builtin_amdgcn_exp2f(2.f * LOG2E * u);
  return x - x * __builtin_amdgcn_rcpf(e2 + 1.f);
}
#define DPP_ADD(v, ctrl, rmask, bc) \
  v += __int_as_float(__builtin_amdgcn_update_dpp(0, __float_as_int(v), (ctrl), (rmask), 0xf, (bc)))
// full-wave (64-lane) sum via DPP, broadcast to all lanes through SGPR
__device__ __forceinline__ float wsum64(float v){
  DPP_ADD(v, 0x111, 0xf, true);
  DPP_ADD(v, 0x112, 0xf, true);
  DPP_ADD(v, 0x114, 0xf, true);
  DPP_ADD(v, 0x118, 0xf, true);
  DPP_ADD(v, 0x142, 0xa, false);
  DPP_ADD(v, 0x143, 0xc, false);
  return bcastf(v, 63);
}

// ---------------- weight conversion ----------------
// w1T/w2T/gifT/gzoT as before. rkf: frag-ready hi/lo split of Rk^T:
// rkf[(nb*4+h)][m(8)][lane(64)][j0..7 = hi, j8..15 = lo] u16,
// value(m,l,j) = Rk[dim=(l>>4)*8+j][gate=m*16+(l&15)] (A-frag for 16x16x32).
__global__ __launch_bounds__(256) void k_convert(
    const float* __restrict__ ff_w1, const float* __restrict__ ff_w2,
    const float* __restrict__ Wi, const float* __restrict__ Wf,
    const float* __restrict__ Wz, const float* __restrict__ Wo,
    const float* __restrict__ Rk,
    u16* __restrict__ w1T, u16* __restrict__ w2T,
    u16* __restrict__ gifT, u16* __restrict__ gzoT, u16* __restrict__ rkf){
  int tid = blockIdx.x * 256 + threadIdx.x;
  const int n1 = NBB*384*128;
  if (tid < n1){
    int nb = tid / (384*128); int r = tid - nb*384*128; int n = r >> 7, k = r & 127;
    w1T[tid] = f2bf(ff_w1[(nb*128 + k)*384 + n]); return;
  }
  tid -= n1;
  const int n2 = NBB*128*192;
  if (tid < n2){
    int nb = tid / (128*192); int r = tid - nb*128*192; int n = r / 192, k = r - n*192;
    w2T[tid] = f2bf(ff_w2[(nb*192 + k)*128 + n]); return;
  }
  tid -= n2;
  const int n3 = NBB*HH*64*32;
  if (tid < n3){
    int nb = tid / (HH*64*32); int r = tid - nb*HH*64*32;
    int h = r >> 11; int r2 = r & 2047; int n = r2 >> 5, k = r2 & 31;
    const float* W = (n < 32) ? Wi : Wf; int nn = n & 31;
    gifT[tid] = f2bf(W[((nb*HH + h)*32 + k)*32 + nn]); return;
  }
  tid -= n3;
  if (tid < n3){
    int nb = tid / (HH*64*32); int r = tid - nb*HH*64*32;
    int h = r >> 11; int r2 = r & 2047; int n = r2 >> 5, k = r2 & 31;
    const float* W = (n < 32) ? Wz : Wo; int nn = n & 31;
    gzoT[tid] = f2bf(W[((nb*HH + h)*32 + k)*32 + nn]); return;
  }
  tid -= n3;
  const int n5 = NBB*HH*8*64*8;
  if (tid < n5){
    int j = tid & 7; int t2 = tid >> 3;
    int l = t2 & 63; t2 >>= 6;
    int m = t2 & 7; t2 >>= 3;
    int h4 = t2 & 3; int nb = t2 >> 2;
    float v = Rk[((size_t)((nb*HH + h4)*32) + (l >> 4)*8 + j)*128 + m*16 + (l & 15)];
    u16 hi = f2bf(v);
    u16 lo = f2bf(v - bf2f(hi));
    size_t base = (((size_t)(nb*HH + h4)*8 + m)*64 + l)*16;
    rkf[base + j] = hi;
    rkf[base + 8 + j] = lo;
  }
}

// ---------------- LN1 + causal depthwise conv + silu ----------------
__global__ __launch_bounds__(256) void k_lnconv(float* __restrict__ x,
    const int* __restrict__ tok, const float* __restrict__ emb,
    const float* __restrict__ ln1_w, const float* __restrict__ conv_w,
    const float* __restrict__ conv_b, u16* __restrict__ xn_bf,
    u16* __restrict__ xc_bf, int nb, int useemb){
  __shared__ float lnbuf[35][128];
  int b = blockIdx.x >> 2, tile = blockIdx.x & 3;
  int t0 = tile * 32;
  int wid = threadIdx.x >> 6, l = threadIdx.x & 63;
  for (int tt = wid; tt < 35; tt += 4){
    int t = t0 - 3 + tt;
    if (t < 0){
      lnbuf[tt][2*l] = 0.f; lnbuf[tt][2*l+1] = 0.f;
    } else {
      const float* src = useemb ? (emb + (size_t)tok[b*TT + t]*128)
                                : (x + (size_t)(b*TT + t)*128);
      float2 v = ((const float2*)src)[l];
      float s  = wsum64(v.x + v.y);
      float sq = wsum64(v.x*v.x + v.y*v.y);
      float mu = s * (1.f/128.f);
      float var = sq * (1.f/128.f) - mu*mu;
      float rs = rsqrtf(var + EPSF);
      float2 w = ((const float2*)(ln1_w + nb*128))[l];
      float y0 = (v.x - mu)*rs*w.x, y1 = (v.y - mu)*rs*w.y;
      lnbuf[tt][2*l] = y0; lnbuf[tt][2*l+1] = y1;
      if (tt >= 3){
        u32 pk = (u32)f2bf(y0) | ((u32)f2bf(y1) << 16);
        ((u32*)(xn_bf + (size_t)(b*TT + t)*128))[l] = pk;
        if (useemb) ((float2*)(x + (size_t)(b*TT + t)*128))[l] = v;
      }
    }
  }
  __syncthreads();
  for (int e = threadIdx.x; e < 32*128; e += 256){
    int tt = e >> 7, d = e & 127;
    float s = conv_b[nb*128 + d];
    #pragma unroll
    for (int k = 0; k < 4; k++)
      s += lnbuf[tt + k][d] * conv_w[(nb*128 + d)*4 + k];
    float sig = 1.f / (1.f + __expf(-s));
    xc_bf[(size_t)(b*TT + t0 + tt)*128 + d] = f2bf(s * sig);
  }
}

// ---------------- gate projections (MFMA) ----------------
// Writes scan-fragment layout (+cell_b folded):
// gfrag[g][t][lane][slot], g=(b>>4)*4+h, lane=((gc>>2)&3)*16+(b&15),
// slot=(gc>>4)*4+(gc&3).  One u16 store per value (L2 write-combines).
__global__ __launch_bounds__(256) void k_gates(const u16* __restrict__ xc_bf,
    const u16* __restrict__ xn_bf, const u16* __restrict__ gifT,
    const u16* __restrict__ gzoT, const float* __restrict__ cell_b,
    u16* __restrict__ gfrag, int nb){
  int m0 = blockIdx.x * 64;
  int b = m0 >> 7;
  int t00 = m0 & 127;
  int h = threadIdx.x >> 6, l = threadIdx.x & 63;
  short8 bfr[2][4];
  {
    const u16* B0 = gifT + (size_t)(nb*HH + h)*64*32;
    const u16* B1 = gzoT + (size_t)(nb*HH + h)*64*32;
    #pragma unroll
    for (int jt = 0; jt < 4; jt++){
      bfr[0][jt] = *(const short8*)(B0 + (jt*16 + (l & 15))*32 + (l >> 4)*8);
      bfr[1][jt] = *(const short8*)(B1 + (jt*16 + (l & 15))*32 + (l >> 4)*8);
    }
  }
  u16* gf = gfrag + (size_t)((b >> 4)*4 + h)*TT*64*32;
  int c = b & 15;
  int gg = (l & 15) >> 2;
  int r3 = l & 3;
  const float* cbp = cell_b + (nb*HH + h)*128;
  #pragma unroll
  for (int z = 0; z < 2; z++){
    const u16* A = z ? xn_bf : xc_bf;
    #pragma unroll
    for (int rg = 0; rg < 4; rg++){
      int r0 = m0 + rg*16;
      short8 a = *(const short8*)(A + (size_t)(r0 + (l & 15))*128 + h*32 + (l >> 4)*8);
      int tb = t00 + rg*16 + (l >> 4)*4;
      #pragma unroll
      for (int jt = 0; jt < 4; jt++){
        f32x4 acc = {0.f, 0.f, 0.f, 0.f};
        acc = __builtin_amdgcn_mfma_f32_16x16x32_bf16(a, bfr[z][jt], acc, 0, 0, 0);
        int cloc = z*64 + jt*16 + (l & 15);
        float cb = cbp[cloc];
        int slot = (z*4 + jt)*4 + r3;
        #pragma unroll
        for (int r = 0; r < 4; r++)
          gf[((size_t)(tb + r)*64 + gg*16 + c)*32 + slot] = f2bf(acc[r] + cb);
      }
    }
  }
}

// ---------------- sLSTM scan via MFMA over 16-chain groups ----------------
// wave g: head g&3, batches (g>>2)*16..+15.  A = Rk^T tiles (hi/lo bf16 split,
// constant).  Per step: C = gates + Rk_hi*h_hi + Rk_hi*h_lo + Rk_lo*h_hi (3x8
// MFMA), lane-local gating for 8 (elem) slots of chain c=l&15, GN via shfl,
// h -> bf16 hi/lo B-frag via 2.5KB LDS transpose.
__global__ __launch_bounds__(64, 1) void k_scan(const u16* __restrict__ gfrag,
    const u16* __restrict__ rkf, const float* __restrict__ gn_w,
    float* __restrict__ x, int nb){
  __shared__ u16 hb[2][16][40];   // [hi/lo][chain][32 dims + pad]
  int l = threadIdx.x;
  int g = blockIdx.x;
  int hg = g & 3;
  int c = l & 15, g2 = l >> 4;
  int b = (g >> 2)*16 + c;
  short8 afh[8], afl[8];
  {
    const u16* rk = rkf + (((size_t)(nb*HH + hg)*8)*64 + l)*16;
    #pragma unroll
    for (int m = 0; m < 8; m++){
      afh[m] = *(const short8*)(rk + (size_t)m*64*16);
      afl[m] = *(const short8*)(rk + (size_t)m*64*16 + 8);
    }
  }
  float gnw[8];
  #pragma unroll
  for (int r = 0; r < 4; r++){
    gnw[r]     = gn_w[nb*128 + hg*32 + 4*g2 + r];
    gnw[4 + r] = gn_w[nb*128 + hg*32 + 16 + 4*g2 + r];
  }
  float cs[8], ns[8], ms[8];
  #pragma unroll
  for (int i = 0; i < 8; i++){ cs[i] = 0.f; ns[i] = 0.f; ms[i] = 0.f; }
  short8 bh = {0,0,0,0,0,0,0,0}, bl = {0,0,0,0,0,0,0,0};
  const u16* gp = gfrag + ((size_t)g*TT*64 + l)*32;
  float* xrow = x + (size_t)b*TT*128 + hg*32;
  short8 gv0 = ((const short8*)gp)[0], gv1 = ((const short8*)gp)[1],
         gv2 = ((const short8*)gp)[2], gv3 = ((const short8*)gp)[3];
  f32x4 xn0 = *(const f32x4*)(xrow + 4*g2);
  f32x4 xn1 = *(const f32x4*)(xrow + 16 + 4*g2);
  for (int t = 0; t < TT; t++){
    // prefetch next step (overreads at very end -- ws mapped)
    const u16* gpn = gp + 64*32;
    short8 pg0 = ((const short8*)gpn)[0], pg1 = ((const short8*)gpn)[1],
           pg2 = ((const short8*)gpn)[2], pg3 = ((const short8*)gpn)[3];
    f32x4 xf0 = *(const f32x4*)(xrow + 128 + 4*g2);
    f32x4 xf1 = *(const f32x4*)(xrow + 128 + 16 + 4*g2);
    // C init from gates (+cell_b already folded)
    f32x4 C[8];
    #pragma unroll
    for (int r = 0; r < 4; r++){
      C[0][r] = bf2f((u16)gv0[r]); C[1][r] = bf2f((u16)gv0[4+r]);
      C[2][r] = bf2f((u16)gv1[r]); C[3][r] = bf2f((u16)gv1[4+r]);
      C[4][r] = bf2f((u16)gv2[r]); C[5][r] = bf2f((u16)gv2[4+r]);
      C[6][r] = bf2f((u16)gv3[r]); C[7][r] = bf2f((u16)gv3[4+r]);
    }
    #pragma unroll
    for (int m = 0; m < 8; m++){
      C[m] = __builtin_amdgcn_mfma_f32_16x16x32_bf16(afh[m], bh, C[m], 0, 0, 0);
      C[m] = __builtin_amdgcn_mfma_f32_16x16x32_bf16(afh[m], bl, C[m], 0, 0, 0);
      C[m] = __builtin_amdgcn_mfma_f32_16x16x32_bf16(afl[m], bh, C[m], 0, 0, 0);
    }
    // gating: 8 lane-local (elem) slots of chain c
    float hs[8];
    #pragma unroll
    for (int hf = 0; hf < 2; hf++){
      #pragma unroll
      for (int r = 0; r < 4; r++){
        int i = hf*4 + r;
        float ir = C[0+hf][r], fr = C[2+hf][r], zr = C[4+hf][r], og = C[6+hf][r];
        float a = fr + ms[i];
        float mnew = fmaxf(a, ir);
        float mL = mnew * LOG2E;
        float ig = __builtin_amdgcn_exp2f(fmaf(ir, LOG2E, -mL));
        float fg = __builtin_amdgcn_exp2f(fmaf(a, LOG2E, -mL));
        float e2 = __builtin_amdgcn_exp2f(zr * (2.f*LOG2E));
        float th = fmaf(-2.f, __builtin_amdgcn_rcpf(e2 + 1.f), 1.f);
        cs[i] = fmaf(fg, cs[i], ig * th);
        ns[i] = fmaf(fg, ns[i], ig);
        ms[i] = mnew;
        float se = __builtin_amdgcn_exp2f(og * -LOG2E);
        hs[i] = cs[i] * __builtin_amdgcn_rcpf(fmaf(ns[i], se, ns[i]));
      }
    }
    // split h into bf16 hi/lo, transpose via LDS into next step's B-frags
    #pragma unroll
    for (int hf = 0; hf < 2; hf++){
      u32 h01, h23, l01, l23;
      asm("v_cvt_pk_bf16_f32 %0, %1, %2" : "=v"(h01) : "v"(hs[hf*4+0]), "v"(hs[hf*4+1]));
      asm("v_cvt_pk_bf16_f32 %0, %1, %2" : "=v"(h23) : "v"(hs[hf*4+2]), "v"(hs[hf*4+3]));
      float hi0 = __uint_as_float(h01 << 16);
      float hi1 = __uint_as_float(h01 & 0xffff0000u);
      float hi2 = __uint_as_float(h23 << 16);
      float hi3 = __uint_as_float(h23 & 0xffff0000u);
      float d0 = hs[hf*4+0] - hi0, d1 = hs[hf*4+1] - hi1;
      float d2 = hs[hf*4+2] - hi2, d3 = hs[hf*4+3] - hi3;
      asm("v_cvt_pk_bf16_f32 %0, %1, %2" : "=v"(l01) : "v"(d0), "v"(d1));
      asm("v_cvt_pk_bf16_f32 %0, %1, %2" : "=v"(l23) : "v"(d2), "v"(d3));
      *(uint2*)(&hb[0][c][hf*16 + 4*g2]) = make_uint2(h01, h23);
      *(uint2*)(&hb[1][c][hf*16 + 4*g2]) = make_uint2(l01, l23);
    }
    __builtin_amdgcn_sched_barrier(0);
    asm volatile("s_waitcnt lgkmcnt(0)" ::: "memory");
    __builtin_amdgcn_sched_barrier(0);
    bh = *(const short8*)(&hb[0][c][g2*8]);
    bl = *(const short8*)(&hb[1][c][g2*8]);
    // group norm (off the recurrence path) + residual write
    float s8 = 0.f, sq8 = 0.f;
    #pragma unroll
    for (int i = 0; i < 8; i++){ s8 += hs[i]; sq8 += hs[i]*hs[i]; }
    s8 += __shfl_xor(s8, 32, 64);  sq8 += __shfl_xor(sq8, 32, 64);
    s8 += __shfl_xor(s8, 16, 64);  sq8 += __shfl_xor(sq8, 16, 64);
    float mu = s8 * (1.f/32.f);
    float var = sq8 * (1.f/32.f) - mu*mu;
    float rs = __builtin_amdgcn_rsqf(var + EPSF);
    f32x4 o0, o1;
    #pragma unroll
    for (int r = 0; r < 4; r++){
      o0[r] = xn0[r] + (hs[r]   - mu)*rs*gnw[r];
      o1[r] = xn1[r] + (hs[4+r] - mu)*rs*gnw[4+r];
    }
    *(f32x4*)(xrow + 4*g2) = o0;
    *(f32x4*)(xrow + 16 + 4*g2) = o1;
    xrow += 128; gp = gpn;
    gv0 = pg0; gv1 = pg1; gv2 = pg2; gv3 = pg3;
    xn0 = xf0; xn1 = xf1;
  }
}

// ---------------- fused LN2 + FFN (N-partitioned, W loaded once/block) -------
__global__ __launch_bounds__(512, 4) void k_ffn(float* __restrict__ x,
    const float* __restrict__ ln2_w, const u16* __restrict__ w1T,
    const float* __restrict__ ff_b1, const u16* __restrict__ w2T,
    const float* __restrict__ ff_b2, int nb){
  __shared__ u16 xln[64][136];
  __shared__ u16 hbuf[64][392];
  int m0 = blockIdx.x * 64;
  int w = threadIdx.x >> 6, l = threadIdx.x & 63;
  short8 w1f[3][4];
  const u16* W1 = w1T + (size_t)nb*384*128;
  #pragma unroll
  for (int j = 0; j < 3; j++)
    #pragma unroll
    for (int c = 0; c < 4; c++)
      w1f[j][c] = *(const short8*)(W1 + (size_t)((3*w + j)*16 + (l & 15))*128 + c*32 + (l >> 4)*8);
  short8 w2f[6];
  const u16* W2 = w2T + (size_t)nb*128*192;
  #pragma unroll
  for (int c = 0; c < 6; c++)
    w2f[c] = *(const short8*)(W2 + (size_t)(w*16 + (l & 15))*192 + c*32 + (l >> 4)*8);
  float2 lw = ((const float2*)(ln2_w + nb*128))[l];
  #pragma unroll
  for (int rr = 0; rr < 8; rr++){
    int row = w*8 + rr;
    float2 v = ((const float2*)(x + (size_t)(m0 + row)*128))[l];
    float s  = wsum64(v.x + v.y);
    float sq = wsum64(v.x*v.x + v.y*v.y);
    float mu = s * (1.f/128.f);
    float var = sq * (1.f/128.f) - mu*mu;
    float rs = rsqrtf(var + EPSF);
    ((u32*)xln[row])[l] = (u32)f2bf((v.x - mu)*rs*lw.x)
                        | ((u32)f2bf((v.y - mu)*rs*lw.y) << 16);
  }
  __syncthreads();
  #pragma unroll
  for (int rg = 0; rg < 4; rg++){
    short8 a[4];
    #pragma unroll
    for (int c = 0; c < 4; c++)
      a[c] = *(const short8*)(&xln[rg*16 + (l & 15)][c*32 + (l >> 4)*8]);
    #pragma unroll
    for (int j = 0; j < 3; j++){
      f32x4 acc = {0.f, 0.f, 0.f, 0.f};
      #pragma unroll
      for (int c = 0; c < 4; c++)
        acc = __builtin_amdgcn_mfma_f32_16x16x32_bf16(a[c], w1f[j][c], acc, 0, 0, 0);
      int col = (3*w + j)*16 + (l & 15);
      float bb = ff_b1[nb*384 + col];
      #pragma unroll
      for (int r = 0; r < 4; r++){
        int row = rg*16 + (l >> 4)*4 + r;
        hbuf[row][col] = f2bf(acc[r] + bb);
      }
    }
  }
  __syncthreads();
  {
    int row = threadIdx.x >> 3;
    int k0 = (threadIdx.x & 7) * 24;
    #pragma unroll
    for (int j2 = 0; j2 < 24; j2++){
      int k = k0 + j2;
      float gt = bf2f(hbuf[row][k]);
      float u = bf2f(hbuf[row][k + 192]);
      hbuf[row][k] = f2bf(gelu_fast(gt) * u);
    }
  }
  __syncthreads();
  #pragma unroll
  for (int rg = 0; rg < 4; rg++){
    f32x4 acc = {0.f, 0.f, 0.f, 0.f};
    #pragma unroll
    for (int c = 0; c < 6; c++){
      short8 a = *(const short8*)(&hbuf[rg*16 + (l & 15)][c*32 + (l >> 4)*8]);
      acc = __builtin_amdgcn_mfma_f32_16x16x32_bf16(a, w2f[c], acc, 0, 0, 0);
    }
    int col = w*16 + (l & 15);
    float bb = ff_b2[nb*128 + col];
    #pragma unroll
    for (int r = 0; r < 4; r++){
      int row = m0 + rg*16 + (l >> 4)*4 + r;
      x[(size_t)row*128 + col] += acc[r] + bb;
    }
  }
}

// ---------------- post-LN + mean-pool + classifier ----------------
__global__ __launch_bounds__(256) void k_pool_cls(const float* __restrict__ x,
    const float* __restrict__ pw, const float* __restrict__ w1,
    const float* __restrict__ b1, const float* __restrict__ w2,
    const float* __restrict__ b2, float* __restrict__ out){
  __shared__ float red[4][128];
  __shared__ float pooled[128];
  __shared__ float h1s[64];
  int b = blockIdx.x;
  int wid = threadIdx.x >> 6, l = threadIdx.x & 63;
  float2 w = ((const float2*)pw)[l];
  float ax = 0.f, ay = 0.f;
  for (int t = wid; t < TT; t += 4){
    float2 v = ((const float2*)(x + (size_t)(b*TT + t)*128))[l];
    float s  = wsum64(v.x + v.y);
    float sq = wsum64(v.x*v.x + v.y*v.y);
    float mu = s * (1.f/128.f);
    float var = sq * (1.f/128.f) - mu*mu;
    float rs = rsqrtf(var + EPSF);
    ax += (v.x - mu)*rs*w.x;
    ay += (v.y - mu)*rs*w.y;
  }
  red[wid][2*l] = ax; red[wid][2*l+1] = ay;
  __syncthreads();
  if (threadIdx.x < 128){
    int d = threadIdx.x;
    pooled[d] = (red[0][d] + red[1][d] + red[2][d] + red[3][d]) * (1.f/128.f);
  }
  __syncthreads();
  if (threadIdx.x < 64){
    int j = threadIdx.x;
    float s = b1[j];
    for (int d = 0; d < 128; d++) s += pooled[d] * w1[d*64 + j];
    h1s[j] = fmaxf(s, 0.f);
  }
  __syncthreads();
  if (threadIdx.x < 2){
    int j = threadIdx.x;
    float s = b2[j];
    for (int k = 0; k < 64; k++) s += h1s[k] * w2[k*2 + j];
    out[b*2 + j] = s;
  }
}

extern "C" void kernel_launch(void* const* d_in, const int* in_sizes, int n_in,
                              void* d_out, int out_size, void* d_ws, size_t ws_size,
                              hipStream_t stream){
  const int*   tok    = (const int*)d_in[0];
  const float* emb    = (const float*)d_in[1];
  const float* ln1_w  = (const float*)d_in[2];
  const float* conv_w = (const float*)d_in[3];
  const float* conv_b = (const float*)d_in[4];
  const float* Wi     = (const float*)d_in[5];
  const float* Wf     = (const float*)d_in[6];
  const float* Wz     = (const float*)d_in[7];
  const float* Wo     = (const float*)d_in[8];
  const float* Rk     = (const float*)d_in[9];
  const float* cell_b = (const float*)d_in[10];
  const float* gn_w   = (const float*)d_in[11];
  const float* ln2_w  = (const float*)d_in[12];
  const float* ff_w1  = (const float*)d_in[13];
  const float* ff_b1  = (const float*)d_in[14];
  const float* ff_w2  = (const float*)d_in[15];
  const float* ff_b2  = (const float*)d_in[16];
  const float* postw  = (const float*)d_in[17];
  const float* cw1    = (const float*)d_in[18];
  const float* cb1    = (const float*)d_in[19];
  const float* cw2    = (const float*)d_in[20];
  const float* cb2    = (const float*)d_in[21];
  float* out = (float*)d_out;

  char* ws = (char*)d_ws;
  size_t off = 0;
  float* x      = (float*)(ws + off); off += (size_t)BT*128*4;
  u16*   xn_bf  = (u16*)(ws + off);   off += (size_t)BT*128*2;
  u16*   xc_bf  = (u16*)(ws + off);   off += (size_t)BT*128*2;
  u16*   gfrag  = (u16*)(ws + off);   off += (size_t)128*TT*64*32*2;   // 67.1MB
  u16*   w1T    = (u16*)(ws + off);   off += (size_t)NBB*384*128*2;
  u16*   w2T    = (u16*)(ws + off);   off += (size_t)NBB*128*192*2;
  u16*   gifT   = (u16*)(ws + off);   off += (size_t)NBB*HH*64*32*2;
  u16*   gzoT   = (u16*)(ws + off);   off += (size_t)NBB*HH*64*32*2;
  u16*   rkf    = (u16*)(ws + off);   off += (size_t)NBB*HH*8*64*16*2;

  k_convert<<<832, 256, 0, stream>>>(ff_w1, ff_w2, Wi, Wf, Wz, Wo, Rk,
                                     w1T, w2T, gifT, gzoT, rkf);
  for (int nb = 0; nb < NBB; nb++){
    k_lnconv<<<BB*4, 256, 0, stream>>>(x, tok, emb, ln1_w, conv_w, conv_b,
                                       xn_bf, xc_bf, nb, nb == 0 ? 1 : 0);
    k_gates<<<BT/64, 256, 0, stream>>>(xc_bf, xn_bf, gifT, gzoT, cell_b, gfrag, nb);
    k_scan<<<128, 64, 0, stream>>>(gfrag, rkf, gn_w, x, nb);
    k_ffn<<<BT/64, 512, 0, stream>>>(x, ln2_w, w1T, ff_b1, w2T, ff_b2, nb);
  }
  k_pool_cls<<<BB, 256, 0, stream>>>(x, postw, cw1, cb1, cw2, cb2, out);
}

// Round 13
// 323.473 us; speedup vs baseline: 1.8028x; 1.8028x over previous
//
#include <hip/hip_runtime.h>

typedef unsigned short u16;
typedef unsigned int u32;
typedef __attribute__((ext_vector_type(8))) short short8;
typedef __attribute__((ext_vector_type(4))) short s16x4;
typedef __attribute__((ext_vector_type(4))) float f32x4;
typedef __attribute__((ext_vector_type(2))) float f32x2;
typedef __attribute__((ext_vector_type(2))) int i32x2;

#define BB 512
#define TT 128
#define DD 128
#define HH 4
#define NBB 2
#define BT (BB*TT)
#define EPSF 1e-5f
#define LOG2E 1.4426950408889634f

__device__ __forceinline__ float bf2f(u16 u){ return __uint_as_float(((u32)u) << 16); }
__device__ __forceinline__ u16 f2bf(float f){
  u32 x = __float_as_uint(f);
  u32 r = x + 0x7fffu + ((x >> 16) & 1u);
  return (u16)(r >> 16);
}
__device__ __forceinline__ float bcastf(float v, int lane){
  return __uint_as_float(__builtin_amdgcn_readlane(__float_as_uint(v), lane));
}
// gelu (tanh approx) with rcp/exp2 only
__device__ __forceinline__ float gelu_fast(float x){
  float u = 0.7978845608028654f * (x + 0.044715f * x * x * x);
  float e2 = __builtin_amdgcn_exp2f(2.f * LOG2E * u);
  return x - x * __builtin_amdgcn_rcpf(e2 + 1.f);
}
#define DPP_ADD(v, ctrl, rmask, bc) \
  v += __int_as_float(__builtin_amdgcn_update_dpp(0, __float_as_int(v), (ctrl), (rmask), 0xf, (bc)))
// full-wave (64-lane) sum via DPP, broadcast to all lanes through SGPR
__device__ __forceinline__ float wsum64(float v){
  DPP_ADD(v, 0x111, 0xf, true);
  DPP_ADD(v, 0x112, 0xf, true);
  DPP_ADD(v, 0x114, 0xf, true);
  DPP_ADD(v, 0x118, 0xf, true);
  DPP_ADD(v, 0x142, 0xa, false);
  DPP_ADD(v, 0x143, 0xc, false);
  return bcastf(v, 63);
}
// sum over lanes 0..31; total lands in lane 31
__device__ __forceinline__ float rsum_rows01(float v){
  DPP_ADD(v, 0x111, 0xf, true);
  DPP_ADD(v, 0x112, 0xf, true);
  DPP_ADD(v, 0x114, 0xf, true);
  DPP_ADD(v, 0x118, 0xf, true);
  DPP_ADD(v, 0x142, 0xa, false);
  return v;
}
// lanes<32 receive v from lane+32 (VALU permlane32_swap; no LDS).
__device__ __forceinline__ float down32(float v){
  i32x2 r = __builtin_amdgcn_permlane32_swap(__float_as_int(v), __float_as_int(v), false, false);
  return __int_as_float(r.y);
}

// ---------------- weight conversion to bf16 (transposed for MFMA B-frags) ----
__global__ __launch_bounds__(256) void k_convert(
    const float* __restrict__ ff_w1, const float* __restrict__ ff_w2,
    const float* __restrict__ Wi, const float* __restrict__ Wf,
    const float* __restrict__ Wz, const float* __restrict__ Wo,
    u16* __restrict__ w1T, u16* __restrict__ w2T,
    u16* __restrict__ gifT, u16* __restrict__ gzoT){
  int tid = blockIdx.x * 256 + threadIdx.x;
  const int n1 = NBB*384*128;
  if (tid < n1){
    int nb = tid / (384*128); int r = tid - nb*384*128; int n = r >> 7, k = r & 127;
    w1T[tid] = f2bf(ff_w1[(nb*128 + k)*384 + n]); return;
  }
  tid -= n1;
  const int n2 = NBB*128*192;
  if (tid < n2){
    int nb = tid / (128*192); int r = tid - nb*128*192; int n = r / 192, k = r - n*192;
    w2T[tid] = f2bf(ff_w2[(nb*192 + k)*128 + n]); return;
  }
  tid -= n2;
  const int n3 = NBB*HH*64*32;
  if (tid < n3){
    int nb = tid / (HH*64*32); int r = tid - nb*HH*64*32;
    int h = r >> 11; int r2 = r & 2047; int n = r2 >> 5, k = r2 & 31;
    const float* W = (n < 32) ? Wi : Wf; int nn = n & 31;
    gifT[tid] = f2bf(W[((nb*HH + h)*32 + k)*32 + nn]); return;
  }
  tid -= n3;
  if (tid < n3){
    int nb = tid / (HH*64*32); int r = tid - nb*HH*64*32;
    int h = r >> 11; int r2 = r & 2047; int n = r2 >> 5, k = r2 & 31;
    const float* W = (n < 32) ? Wz : Wo; int nn = n & 31;
    gzoT[tid] = f2bf(W[((nb*HH + h)*32 + k)*32 + nn]); return;
  }
}

// ---------------- LN1 + causal depthwise conv + silu ----------------
__global__ __launch_bounds__(256) void k_lnconv(float* __restrict__ x,
    const int* __restrict__ tok, const float* __restrict__ emb,
    const float* __restrict__ ln1_w, const float* __restrict__ conv_w,
    const float* __restrict__ conv_b, u16* __restrict__ xn_bf,
    u16* __restrict__ xc_bf, int nb, int useemb){
  __shared__ float lnbuf[35][128];
  int b = blockIdx.x >> 2, tile = blockIdx.x & 3;
  int t0 = tile * 32;
  int wid = threadIdx.x >> 6, l = threadIdx.x & 63;
  for (int tt = wid; tt < 35; tt += 4){
    int t = t0 - 3 + tt;
    if (t < 0){
      lnbuf[tt][2*l] = 0.f; lnbuf[tt][2*l+1] = 0.f;
    } else {
      const float* src = useemb ? (emb + (size_t)tok[b*TT + t]*128)
                                : (x + (size_t)(b*TT + t)*128);
      float2 v = ((const float2*)src)[l];
      float s  = wsum64(v.x + v.y);
      float sq = wsum64(v.x*v.x + v.y*v.y);
      float mu = s * (1.f/128.f);
      float var = sq * (1.f/128.f) - mu*mu;
      float rs = rsqrtf(var + EPSF);
      float2 w = ((const float2*)(ln1_w + nb*128))[l];
      float y0 = (v.x - mu)*rs*w.x, y1 = (v.y - mu)*rs*w.y;
      lnbuf[tt][2*l] = y0; lnbuf[tt][2*l+1] = y1;
      if (tt >= 3){
        u32 pk = (u32)f2bf(y0) | ((u32)f2bf(y1) << 16);
        ((u32*)(xn_bf + (size_t)(b*TT + t)*128))[l] = pk;
        if (useemb) ((float2*)(x + (size_t)(b*TT + t)*128))[l] = v;
      }
    }
  }
  __syncthreads();
  for (int e = threadIdx.x; e < 32*128; e += 256){
    int tt = e >> 7, d = e & 127;
    float s = conv_b[nb*128 + d];
    #pragma unroll
    for (int k = 0; k < 4; k++)
      s += lnbuf[tt + k][d] * conv_w[(nb*128 + d)*4 + k];
    float sig = 1.f / (1.f + __expf(-s));
    xc_bf[(size_t)(b*TT + t0 + tt)*128 + d] = f2bf(s * sig);
  }
}

// ---------------- gate projections (MFMA) ----------------
// grid BT/64; wave wid = head h; handles z=0,1 and 4 row-groups (32 MFMA/wave)
// gates layout: [b][h][t>>3][col(128)][t&7]
__global__ __launch_bounds__(256) void k_gates(const u16* __restrict__ xc_bf,
    const u16* __restrict__ xn_bf, const u16* __restrict__ gifT,
    const u16* __restrict__ gzoT, u16* __restrict__ gates, int nb){
  int m0 = blockIdx.x * 64;
  int b = m0 >> 7;
  int t00 = m0 & 127;
  int h = threadIdx.x >> 6, l = threadIdx.x & 63;
  short8 bfr[2][4];
  {
    const u16* B0 = gifT + (size_t)(nb*HH + h)*64*32;
    const u16* B1 = gzoT + (size_t)(nb*HH + h)*64*32;
    #pragma unroll
    for (int jt = 0; jt < 4; jt++){
      bfr[0][jt] = *(const short8*)(B0 + (jt*16 + (l & 15))*32 + (l >> 4)*8);
      bfr[1][jt] = *(const short8*)(B1 + (jt*16 + (l & 15))*32 + (l >> 4)*8);
    }
  }
  u16* gb = gates + (size_t)(b*HH + h)*TT*128;
  #pragma unroll
  for (int z = 0; z < 2; z++){
    const u16* A = z ? xn_bf : xc_bf;
    #pragma unroll
    for (int rg = 0; rg < 4; rg++){
      int r0 = m0 + rg*16;
      short8 a = *(const short8*)(A + (size_t)(r0 + (l & 15))*128 + h*32 + (l >> 4)*8);
      int tt = t00 + rg*16 + (l >> 4)*4;          // 4-aligned
      #pragma unroll
      for (int jt = 0; jt < 4; jt++){
        f32x4 acc = {0.f, 0.f, 0.f, 0.f};
        acc = __builtin_amdgcn_mfma_f32_16x16x32_bf16(a, bfr[z][jt], acc, 0, 0, 0);
        int cloc = z*64 + jt*16 + (l & 15);
        s16x4 pk;
        #pragma unroll
        for (int r = 0; r < 4; r++) pk[r] = (short)f2bf(acc[r]);
        *(s16x4*)(gb + ((size_t)(tt >> 3)*128 + cloc)*8 + (tt & 7)) = pk;
      }
    }
  }
}

// ---------------- sLSTM recurrent scan + group-norm + residual ----------------
// one wave per (batch, head); lane l owns gate cols l and l+64 (R6/R11 best form).
// lanes<32: (ir, zr); lanes>=32: (fr, og). No LDS/DS ops, no divergence in loop.
__global__ __launch_bounds__(256, 2) void k_scan(const u16* __restrict__ gates,
    const float* __restrict__ Rk, const float* __restrict__ cell_b,
    const float* __restrict__ gn_w, float* __restrict__ x,
    float* __restrict__ dump, int nb){
  int wid = threadIdx.x >> 6, l = threadIdx.x & 63;
  int pair = blockIdx.x * 4 + wid;       // 2048 chains
  int b = pair >> 2, h = pair & 3;
  f32x2 rk[32];
  const float* Rkh = Rk + (size_t)(nb*HH + h)*32*128;
  #pragma unroll
  for (int d = 0; d < 32; d++){
    rk[d].x = Rkh[d*128 + l];
    rk[d].y = Rkh[d*128 + l + 64];
  }
  f32x2 cb = { cell_b[(nb*HH + h)*128 + l], cell_b[(nb*HH + h)*128 + l + 64] };
  int e = l & 31;
  bool lo = (l < 32);
  float gnw = gn_w[nb*128 + h*32 + e];
  float hs = 0.f, cs = 0.f, ns = 0.f, ms = 0.f;
  const u16* gbase = gates + (size_t)(b*HH + h)*TT*128;
  // always-exec residual pointers: hi lanes use a per-wave dump row (stride 0)
  float* xp = lo ? (x + (size_t)(b*TT)*128 + h*32 + e) : (dump + pair*32 + e);
  int xstr = lo ? 128 : 0;
  float xnext = xp[0];
  short8 ga = *(const short8*)(gbase + (size_t)l*8);
  short8 gb = *(const short8*)(gbase + (size_t)(l + 64)*8);
  for (int t8 = 0; t8 < 16; t8++){
    // prefetch next 8 steps (1KB-coalesced per wave; overreads at end — ws mapped)
    short8 na  = *(const short8*)(gbase + ((size_t)(t8+1)*128 + l)*8);
    short8 nb2 = *(const short8*)(gbase + ((size_t)(t8+1)*128 + l + 64)*8);
    #pragma unroll
    for (int k = 0; k < 8; k++){
      float xcur = xnext;
      xnext = xp[xstr];                  // next row (hi lanes: same dump addr)
      f32x2 acc0 = { bf2f((u16)ga[k]) + cb.x, bf2f((u16)gb[k]) + cb.y };
      f32x2 acc1 = {0.f, 0.f}, acc2 = {0.f, 0.f}, acc3 = {0.f, 0.f};
      #pragma unroll
      for (int d = 0; d < 32; d += 4){
        float h0 = bcastf(hs, d),   h1 = bcastf(hs, d+1);
        float h2 = bcastf(hs, d+2), h3 = bcastf(hs, d+3);
        acc0 = __builtin_elementwise_fma((f32x2){h0,h0}, rk[d],   acc0);
        acc1 = __builtin_elementwise_fma((f32x2){h1,h1}, rk[d+1], acc1);
        acc2 = __builtin_elementwise_fma((f32x2){h2,h2}, rk[d+2], acc2);
        acc3 = __builtin_elementwise_fma((f32x2){h3,h3}, rk[d+3], acc3);
      }
      f32x2 rr = (acc0 + acc1) + (acc2 + acc3);
      float r0 = rr.x, r1 = rr.y;          // lanes<32: ir, zr ; lanes>=32: fr, og
      float fx = down32(r0);               // lanes<32 get fr[e]
      float ox = down32(r1);               // lanes<32 get og[e]
      // gating — valid in lanes<32; upper lanes compute garbage (dump-only)
      float mnew = fmaxf(fx + ms, r0);
      float ig = __builtin_amdgcn_exp2f((r0 - mnew) * LOG2E);
      float fg = __builtin_amdgcn_exp2f((fx + ms - mnew) * LOG2E);
      float e2 = __builtin_amdgcn_exp2f(2.f * LOG2E * r1);
      float th = fmaf(-2.f, __builtin_amdgcn_rcpf(e2 + 1.f), 1.f);   // tanh(zr)
      cs = fmaf(fg, cs, ig * th);
      ns = fmaf(fg, ns, ig);
      ms = mnew;
      // hs = cs * sigmoid(og) / ns  with one rcp
      float se = __builtin_amdgcn_exp2f(-ox * LOG2E);
      hs = cs * __builtin_amdgcn_rcpf(fmaf(ns, se, ns));
      // group norm over lanes 0..31 via DPP (no LDS)
      float s = rsum_rows01(hs);
      float sq = rsum_rows01(hs * hs);
      float mu = bcastf(s, 31) * (1.f/32.f);
      float var = bcastf(sq, 31) * (1.f/32.f) - mu*mu;
      float yn = (hs - mu) * __builtin_amdgcn_rsqf(var + EPSF) * gnw;
      xp[0] = xcur + yn;
      xp += xstr;
    }
    ga = na; gb = nb2;
  }
}

// ---------------- fused LN2 + FFN, gelu folded into GEMM1 epilogue ----------
// 8 waves; pair k = (gate tile k, up tile 12+k), cols 16k / 192+16k.
// Wave w: full pair k=w (rg 0..3) + half pair k=8+(w&3) (rg (w>>2)*2 ..+1).
// Every (pair, rg) covered once; 48 MFMAs/wave in GEMM1 (balanced).
__global__ __launch_bounds__(512, 4) void k_ffn(float* __restrict__ x,
    const float* __restrict__ ln2_w, const u16* __restrict__ w1T,
    const float* __restrict__ ff_b1, const u16* __restrict__ w2T,
    const float* __restrict__ ff_b2, int nb){
  __shared__ u16 xln[64][136];
  __shared__ u16 act[64][196];
  int m0 = blockIdx.x * 64;
  int w = threadIdx.x >> 6, l = threadIdx.x & 63;
  int kf = w, kh = 8 + (w & 3);
  int rh0 = (w >> 2) * 2;
  short8 wgf[4], wuf[4], wgh[4], wuh[4];
  const u16* W1 = w1T + (size_t)nb*384*128;
  #pragma unroll
  for (int c = 0; c < 4; c++){
    wgf[c] = *(const short8*)(W1 + (size_t)(kf*16 + (l & 15))*128 + c*32 + (l >> 4)*8);
    wuf[c] = *(const short8*)(W1 + (size_t)((12 + kf)*16 + (l & 15))*128 + c*32 + (l >> 4)*8);
    wgh[c] = *(const short8*)(W1 + (size_t)(kh*16 + (l & 15))*128 + c*32 + (l >> 4)*8);
    wuh[c] = *(const short8*)(W1 + (size_t)((12 + kh)*16 + (l & 15))*128 + c*32 + (l >> 4)*8);
  }
  short8 w2f[6];
  const u16* W2 = w2T + (size_t)nb*128*192;
  #pragma unroll
  for (int c = 0; c < 6; c++)
    w2f[c] = *(const short8*)(W2 + (size_t)(w*16 + (l & 15))*192 + c*32 + (l >> 4)*8);
  // --- LN2 into xln (8 rows per wave)
  float2 lw = ((const float2*)(ln2_w + nb*128))[l];
  #pragma unroll
  for (int rr = 0; rr < 8; rr++){
    int row = w*8 + rr;
    float2 v = ((const float2*)(x + (size_t)(m0 + row)*128))[l];
    float s  = wsum64(v.x + v.y);
    float sq = wsum64(v.x*v.x + v.y*v.y);
    float mu = s * (1.f/128.f);
    float var = sq * (1.f/128.f) - mu*mu;
    float rs = rsqrtf(var + EPSF);
    ((u32*)xln[row])[l] = (u32)f2bf((v.x - mu)*rs*lw.x)
                        | ((u32)f2bf((v.y - mu)*rs*lw.y) << 16);
  }
  __syncthreads();
  // --- GEMM1 + gelu*up fused epilogue
  const float* B1 = ff_b1 + nb*384;
  #pragma unroll
  for (int u5 = 0; u5 < 6; u5++){
    int rg = (u5 < 4) ? u5 : (rh0 + (u5 - 4));
    const short8* wg = (u5 < 4) ? wgf : wgh;
    const short8* wu = (u5 < 4) ? wuf : wuh;
    int k = (u5 < 4) ? kf : kh;
    short8 a[4];
    #pragma unroll
    for (int c = 0; c < 4; c++)
      a[c] = *(const short8*)(&xln[rg*16 + (l & 15)][c*32 + (l >> 4)*8]);
    f32x4 ag = {0.f,0.f,0.f,0.f}, au = {0.f,0.f,0.f,0.f};
    #pragma unroll
    for (int c = 0; c < 4; c++){
      ag = __builtin_amdgcn_mfma_f32_16x16x32_bf16(a[c], wg[c], ag, 0, 0, 0);
      au = __builtin_amdgcn_mfma_f32_16x16x32_bf16(a[c], wu[c], au, 0, 0, 0);
    }
    int col = k*16 + (l & 15);
    float bg = B1[col];
    float bu = B1[192 + col];
    #pragma unroll
    for (int r = 0; r < 4; r++){
      int row = rg*16 + (l >> 4)*4 + r;
      act[row][col] = f2bf(gelu_fast(ag[r] + bg) * (au[r] + bu));
    }
  }
  __syncthreads();
  // --- GEMM2: 64 rows x 16 cols per wave, K=192 from act; + residual
  #pragma unroll
  for (int rg = 0; rg < 4; rg++){
    f32x4 acc = {0.f, 0.f, 0.f, 0.f};
    #pragma unroll
    for (int c = 0; c < 6; c++){
      short8 a = *(const short8*)(&act[rg*16 + (l & 15)][c*32 + (l >> 4)*8]);
      acc = __builtin_amdgcn_mfma_f32_16x16x32_bf16(a, w2f[c], acc, 0, 0, 0);
    }
    int col = w*16 + (l & 15);
    float bb = ff_b2[nb*128 + col];
    #pragma unroll
    for (int r = 0; r < 4; r++){
      int row = m0 + rg*16 + (l >> 4)*4 + r;
      x[(size_t)row*128 + col] += acc[r] + bb;
    }
  }
}

// ---------------- post-LN + mean-pool + classifier ----------------
__global__ __launch_bounds__(256) void k_pool_cls(const float* __restrict__ x,
    const float* __restrict__ pw, const float* __restrict__ w1,
    const float* __restrict__ b1, const float* __restrict__ w2,
    const float* __restrict__ b2, float* __restrict__ out){
  __shared__ float red[4][128];
  __shared__ float pooled[128];
  __shared__ float h1s[64];
  int b = blockIdx.x;
  int wid = threadIdx.x >> 6, l = threadIdx.x & 63;
  float2 w = ((const float2*)pw)[l];
  float ax = 0.f, ay = 0.f;
  for (int t = wid; t < TT; t += 4){
    float2 v = ((const float2*)(x + (size_t)(b*TT + t)*128))[l];
    float s  = wsum64(v.x + v.y);
    float sq = wsum64(v.x*v.x + v.y*v.y);
    float mu = s * (1.f/128.f);
    float var = sq * (1.f/128.f) - mu*mu;
    float rs = rsqrtf(var + EPSF);
    ax += (v.x - mu)*rs*w.x;
    ay += (v.y - mu)*rs*w.y;
  }
  red[wid][2*l] = ax; red[wid][2*l+1] = ay;
  __syncthreads();
  if (threadIdx.x < 128){
    int d = threadIdx.x;
    pooled[d] = (red[0][d] + red[1][d] + red[2][d] + red[3][d]) * (1.f/128.f);
  }
  __syncthreads();
  if (threadIdx.x < 64){
    int j = threadIdx.x;
    float s = b1[j];
    for (int d = 0; d < 128; d++) s += pooled[d] * w1[d*64 + j];
    h1s[j] = fmaxf(s, 0.f);
  }
  __syncthreads();
  if (threadIdx.x < 2){
    int j = threadIdx.x;
    float s = b2[j];
    for (int k = 0; k < 64; k++) s += h1s[k] * w2[k*2 + j];
    out[b*2 + j] = s;
  }
}

extern "C" void kernel_launch(void* const* d_in, const int* in_sizes, int n_in,
                              void* d_out, int out_size, void* d_ws, size_t ws_size,
                              hipStream_t stream){
  const int*   tok    = (const int*)d_in[0];
  const float* emb    = (const float*)d_in[1];
  const float* ln1_w  = (const float*)d_in[2];
  const float* conv_w = (const float*)d_in[3];
  const float* conv_b = (const float*)d_in[4];
  const float* Wi     = (const float*)d_in[5];
  const float* Wf     = (const float*)d_in[6];
  const float* Wz     = (const float*)d_in[7];
  const float* Wo     = (const float*)d_in[8];
  const float* Rk     = (const float*)d_in[9];
  const float* cell_b = (const float*)d_in[10];
  const float* gn_w   = (const float*)d_in[11];
  const float* ln2_w  = (const float*)d_in[12];
  const float* ff_w1  = (const float*)d_in[13];
  const float* ff_b1  = (const float*)d_in[14];
  const float* ff_w2  = (const float*)d_in[15];
  const float* ff_b2  = (const float*)d_in[16];
  const float* postw  = (const float*)d_in[17];
  const float* cw1    = (const float*)d_in[18];
  const float* cb1    = (const float*)d_in[19];
  const float* cw2    = (const float*)d_in[20];
  const float* cb2    = (const float*)d_in[21];
  float* out = (float*)d_out;

  char* ws = (char*)d_ws;
  size_t off = 0;
  float* x      = (float*)(ws + off); off += (size_t)BT*128*4;
  u16*   xn_bf  = (u16*)(ws + off);   off += (size_t)BT*128*2;
  u16*   xc_bf  = (u16*)(ws + off);   off += (size_t)BT*128*2;
  u16*   gates  = (u16*)(ws + off);   off += (size_t)BT*512*2;
  u16*   w1T    = (u16*)(ws + off);   off += (size_t)NBB*384*128*2;
  u16*   w2T    = (u16*)(ws + off);   off += (size_t)NBB*128*192*2;
  u16*   gifT   = (u16*)(ws + off);   off += (size_t)NBB*HH*64*32*2;
  u16*   gzoT   = (u16*)(ws + off);   off += (size_t)NBB*HH*64*32*2;
  float* dump   = (float*)xn_bf;      // dead during k_scan; 256KB used

  k_convert<<<704, 256, 0, stream>>>(ff_w1, ff_w2, Wi, Wf, Wz, Wo, w1T, w2T, gifT, gzoT);
  for (int nb = 0; nb < NBB; nb++){
    k_lnconv<<<BB*4, 256, 0, stream>>>(x, tok, emb, ln1_w, conv_w, conv_b,
                                       xn_bf, xc_bf, nb, nb == 0 ? 1 : 0);
    k_gates<<<BT/64, 256, 0, stream>>>(xc_bf, xn_bf, gifT, gzoT, gates, nb);
    k_scan<<<512, 256, 0, stream>>>(gates, Rk, cell_b, gn_w, x, dump, nb);
    k_ffn<<<BT/64, 512, 0, stream>>>(x, ln2_w, w1T, ff_b1, w2T, ff_b2, nb);
  }
  k_pool_cls<<<BB, 256, 0, stream>>>(x, postw, cw1, cb1, cw2, cb2, out);
}